// Round 1
// baseline (1846.955 us; speedup 1.0000x reference)
//
#include <hip/hip_runtime.h>

#define BATCH 1024
#define TLEN  512
#define HID   128

typedef __attribute__((ext_vector_type(8))) short          bf16x8;
typedef __attribute__((ext_vector_type(4))) float          f32x4;
typedef __attribute__((ext_vector_type(4))) unsigned short u16x4;

__device__ __forceinline__ unsigned short f2bf(float f) {
    union { float f; unsigned u; } v; v.f = f;
    unsigned r = v.u + 0x7fffu + ((v.u >> 16) & 1u);   // RNE
    return (unsigned short)(r >> 16);
}

__device__ __forceinline__ float fast_sigmoid(float x) {
    float e = __expf(-x);
    return __builtin_amdgcn_rcpf(1.0f + e);
}
__device__ __forceinline__ float fast_tanh(float x) {
    float ax = __builtin_fabsf(x);
    float e  = __expf(-2.0f * ax);
    float r  = (1.0f - e) * __builtin_amdgcn_rcpf(1.0f + e);
    return __builtin_copysignf(r, x);
}

// MODE 0: layer 0 (x from d_in, Din=6 padded to 32, NKT=5)
// MODE 1: layers 1/2 (x = prev layer h from hseq, Din=128, NKT=8)
//
// Block: 512 threads = 8 waves, 16 batch rows/block.
// Wave w owns gate columns [16w,16w+16) of each gate i,f,g,o
//   (N-tiles {w, 8+w, 16+w, 24+w}), so i/f/g/o for one (m,j) are in ONE lane.
// A (inputs) staged in LDS in MFMA fragment order: elem[kt*512 + lane*8 + j]
//   = A[m=lane&15][k=kt*32 + (lane>>4)*8 + j]  -> ds_read_b128, conflict-free.
template<int MODE>
__device__ __forceinline__ void run_layer(
    const float* __restrict__ xin,
    unsigned short* __restrict__ hseq,
    const float* __restrict__ wih, const float* __restrict__ whh,
    const float* __restrict__ bih, const float* __restrict__ bhh,
    unsigned short (* __restrict__ Abuf)[8 * 512],
    float* __restrict__ fcred, const int write_fc,
    const int tid, const int wave, const int lane,
    const int n16, const int quad, const int bbase)
{
    constexpr int NKT  = MODE ? 8 : 5;     // K-tiles (32 each)
    constexpr int KX   = MODE ? 128 : 32;  // padded x-region width
    constexpr int DINL = MODE ? 128 : 6;   // real input features

    // ---- weights -> register-resident B fragments (bf16) ----
    bf16x8 Wf[4][NKT];
    float  bb[4];
#pragma unroll
    for (int g = 0; g < 4; ++g) {
        const int row = g * 128 + wave * 16 + n16;   // gate row in [4H]
        bb[g] = bih[row] + bhh[row];
#pragma unroll
        for (int kt = 0; kt < NKT; ++kt) {
            const int kbase = kt * 32 + quad * 8;
            bf16x8 wv;
#pragma unroll
            for (int j = 0; j < 8; ++j) {
                const int k = kbase + j;
                float f;
                if (k < KX) f = (k < DINL) ? wih[row * DINL + k] : 0.0f;
                else        f = whh[row * HID + (k - KX)];
                wv[j] = (short)f2bf(f);
            }
            Wf[g][kt] = wv;
        }
    }

    // ---- stage t=0 into Abuf[0]: zero h-region, load x(0) ----
    {
        const int hb0 = (MODE ? 4 : 1) * 512;        // h-region start elem
        u16x4 z = {0, 0, 0, 0};
        *(u16x4*)&Abuf[0][hb0 + tid * 4] = z;        // 512 thr x 4 = 2048 elems
    }
    if (MODE == 0) {
        const int m = tid >> 5, k = tid & 31;
        float v = (k < 6) ? xin[((bbase + m) * TLEN + 0) * 6 + k] : 0.0f;
        Abuf[0][((k >> 3) * 16 + m) * 8 + (k & 7)] = f2bf(v);
    } else {
        const int m = tid >> 5, k4 = (tid & 31) * 4;
        const unsigned long long* p =
            (const unsigned long long*)&hseq[((bbase + m) * TLEN + 0) * HID + k4];
        unsigned long long v64 =
            __hip_atomic_load(p, __ATOMIC_RELAXED, __HIP_MEMORY_SCOPE_AGENT);
        const int kt = k4 >> 5, kk = k4 & 31;
        *(unsigned long long*)&Abuf[0][kt * 512 + ((kk >> 3) * 16 + m) * 8 + (kk & 7)] = v64;
    }

    float cst[4] = {0.f, 0.f, 0.f, 0.f};   // c state: m = quad*4+r, j = 16*wave+n16

    for (int t = 0; t < TLEN; ++t) {
        const int cur = t & 1, nxt = cur ^ 1;
        __syncthreads();   // Abuf[cur] complete; prior reads of Abuf[nxt] done

        // prefetch x(t+1) early (independent of this step's compute)
        const bool has_next = (t + 1 < TLEN);
        unsigned long long pf64 = 0;
        float pff = 0.0f;
        if (has_next) {
            if (MODE == 0) {
                const int m = tid >> 5, k = tid & 31;
                if (k < 6) pff = xin[((bbase + m) * TLEN + (t + 1)) * 6 + k];
            } else {
                const int m = tid >> 5, k4 = (tid & 31) * 4;
                const unsigned long long* p =
                    (const unsigned long long*)&hseq[((bbase + m) * TLEN + (t + 1)) * HID + k4];
                pf64 = __hip_atomic_load(p, __ATOMIC_RELAXED, __HIP_MEMORY_SCOPE_AGENT);
            }
        }

        // ---- gates = A @ W^T  (fp32 accum) ----
        f32x4 acc[4];
#pragma unroll
        for (int g = 0; g < 4; ++g) { f32x4 z = {0.f, 0.f, 0.f, 0.f}; acc[g] = z; }
#pragma unroll
        for (int kt = 0; kt < NKT; ++kt) {
            bf16x8 a = *(const bf16x8*)&Abuf[cur][kt * 512 + lane * 8];
#pragma unroll
            for (int g = 0; g < 4; ++g)
                acc[g] = __builtin_amdgcn_mfma_f32_16x16x32_bf16(a, Wf[g][kt], acc[g], 0, 0, 0);
        }

        // ---- in-lane LSTM cell update (i,f,g,o all local) ----
        unsigned short hb[4]; float hf[4];
#pragma unroll
        for (int r = 0; r < 4; ++r) {
            const float iv = fast_sigmoid(acc[0][r] + bb[0]);
            const float fv = fast_sigmoid(acc[1][r] + bb[1]);
            const float gv = fast_tanh  (acc[2][r] + bb[2]);
            const float ov = fast_sigmoid(acc[3][r] + bb[3]);
            const float c  = fv * cst[r] + iv * gv;
            cst[r] = c;
            const float h  = ov * fast_tanh(c);
            hf[r] = h;
            hb[r] = f2bf(h);
        }

        // ---- h -> Abuf[nxt] h-region (A-layout) + global hseq ----
        {
            const int j  = wave * 16 + n16;
            const int kh = KX + j;
            const int kt = kh >> 5, kk = kh & 31;
            const int eb = kt * 512 + (kk >> 3) * 128 + (kk & 7);
#pragma unroll
            for (int r = 0; r < 4; ++r) {
                const int m = quad * 4 + r;
                Abuf[nxt][eb + m * 8] = hb[r];
                hseq[((bbase + m) * TLEN + t) * HID + j] = hb[r];
            }
        }
        if (write_fc && t == TLEN - 1) {
#pragma unroll
            for (int r = 0; r < 4; ++r)
                fcred[(quad * 4 + r) * HID + wave * 16 + n16] = hf[r];
        }

        // ---- commit prefetched x(t+1) into Abuf[nxt] x-region ----
        if (has_next) {
            if (MODE == 0) {
                const int m = tid >> 5, k = tid & 31;
                Abuf[nxt][((k >> 3) * 16 + m) * 8 + (k & 7)] = f2bf(pff);
            } else {
                const int m = tid >> 5, k4 = (tid & 31) * 4;
                const int kt = k4 >> 5, kk = k4 & 31;
                *(unsigned long long*)&Abuf[nxt][kt * 512 + ((kk >> 3) * 16 + m) * 8 + (kk & 7)] = pf64;
            }
        }
    }
    __syncthreads();   // layer done before Abuf reuse
}

extern "C" __global__ __launch_bounds__(512, 2)
void lstm3_kernel(const float* __restrict__ xin,
    const float* __restrict__ wih0, const float* __restrict__ whh0,
    const float* __restrict__ bih0, const float* __restrict__ bhh0,
    const float* __restrict__ wih1, const float* __restrict__ whh1,
    const float* __restrict__ bih1, const float* __restrict__ bhh1,
    const float* __restrict__ wih2, const float* __restrict__ whh2,
    const float* __restrict__ bih2, const float* __restrict__ bhh2,
    const float* __restrict__ fcw, const float* __restrict__ fcb,
    float* __restrict__ out, unsigned short* __restrict__ hseq)
{
    __shared__ unsigned short Abuf[2][8 * 512];   // 16 KB: double-buffered A
    __shared__ float fcred[16 * HID];             // 8 KB: final-h for FC

    const int tid   = threadIdx.x;
    const int wave  = tid >> 6;
    const int lane  = tid & 63;
    const int n16   = lane & 15;
    const int quad  = lane >> 4;
    const int bbase = blockIdx.x * 16;

    run_layer<0>(xin, hseq, wih0, whh0, bih0, bhh0, Abuf, fcred, 0,
                 tid, wave, lane, n16, quad, bbase);
    run_layer<1>(nullptr, hseq, wih1, whh1, bih1, bhh1, Abuf, fcred, 0,
                 tid, wave, lane, n16, quad, bbase);
    run_layer<1>(nullptr, hseq, wih2, whh2, bih2, bhh2, Abuf, fcred, 1,
                 tid, wave, lane, n16, quad, bbase);

    __syncthreads();
    if (tid < 16) {
        float s = 0.0f;
#pragma unroll 8
        for (int j = 0; j < HID; ++j) s += fcw[j] * fcred[tid * HID + j];
        out[bbase + tid] = s + fcb[0];
    }
}

extern "C" void kernel_launch(void* const* d_in, const int* in_sizes, int n_in,
                              void* d_out, int out_size, void* d_ws, size_t ws_size,
                              hipStream_t stream) {
    (void)in_sizes; (void)n_in; (void)out_size; (void)ws_size;
    const float* x    = (const float*)d_in[0];
    const float* wih0 = (const float*)d_in[1];
    const float* whh0 = (const float*)d_in[2];
    const float* bih0 = (const float*)d_in[3];
    const float* bhh0 = (const float*)d_in[4];
    const float* wih1 = (const float*)d_in[5];
    const float* whh1 = (const float*)d_in[6];
    const float* bih1 = (const float*)d_in[7];
    const float* bhh1 = (const float*)d_in[8];
    const float* wih2 = (const float*)d_in[9];
    const float* whh2 = (const float*)d_in[10];
    const float* bih2 = (const float*)d_in[11];
    const float* bhh2 = (const float*)d_in[12];
    const float* fcw  = (const float*)d_in[13];
    const float* fcb  = (const float*)d_in[14];
    float* out = (float*)d_out;
    unsigned short* hseq = (unsigned short*)d_ws;   // [B][T][H] bf16 = 134 MB

    lstm3_kernel<<<dim3(64), dim3(512), 0, stream>>>(
        x, wih0, whh0, bih0, bhh0, wih1, whh1, bih1, bhh1,
        wih2, whh2, bih2, bhh2, fcw, fcb, out, hseq);
}